// Round 8
// baseline (150.881 us; speedup 1.0000x reference)
//
#include <hip/hip_runtime.h>
#include <hip/hip_bf16.h>

// Capsule dynamic routing, factored (no u_hat), MFMA + async LDS staging.
// B=64, N=2048, D=64, I=32, J=16.
// Round 8: kbig was HBM-latency-bound (r7: all pipes <5%, 52-55us floor
// across 4 structures). Stage u-slice (32KB) + w~ (8KB) per block via
// global_load_lds (deep async MLP), feed both MFMA phases from LDS.
// Source-side 16B-granule XOR swizzle (^row&14) => conflict-free reads.
// No global atomics anywhere -> no memset dispatch.

#define BB 64
#define NN 2048
#define DD 64
#define II 32
#define JJ 16
#define CHROWS 128            // rows per kbig block (4 waves x 32 rows)
#define NCH (NN / CHROWS)     // 16 chunks per batch

typedef __attribute__((ext_vector_type(8)))  short bf16x8;
typedef __attribute__((ext_vector_type(16))) float f32x16;

__device__ __forceinline__ short f2bf(float f) {
    __hip_bfloat16 h = __float2bfloat16(f);
    return *reinterpret_cast<short*>(&h);
}
__device__ __forceinline__ float bf2f(short s) {
    __hip_bfloat16 h = *reinterpret_cast<__hip_bfloat16*>(&s);
    return __bfloat162float(h);
}
__device__ __forceinline__ void gload_lds16(float* lds, const float* g) {
    __builtin_amdgcn_global_load_lds(
        (const __attribute__((address_space(1))) void*)g,
        (__attribute__((address_space(3))) void*)lds, 16, 0, 0);
}

// ---------------- kernel 1: spart[cb][b][d] = sum of 64 rows ----------------
__global__ __launch_bounds__(256) void ksum(const float* __restrict__ u,
                                            float* __restrict__ spart) {
    int b = blockIdx.y, cb = blockIdx.x;        // cb: 0..31, 64 rows each
    int tid = threadIdx.x, cg = tid & 15, rr = tid >> 4;
    const float4* up = reinterpret_cast<const float4*>(
        u + ((size_t)b * NN + (size_t)cb * 64 + rr) * DD) + cg;
    float4 a = {0.f, 0.f, 0.f, 0.f};
    #pragma unroll
    for (int k = 0; k < 4; ++k) {               // rows rr + 16k
        float4 v = up[(size_t)k * 16 * (DD / 4)];
        a.x += v.x; a.y += v.y; a.z += v.z; a.w += v.w;
    }
    __shared__ float4 red[16][16];
    red[rr][cg] = a;
    __syncthreads();
    if (rr == 0) {
        float4 s = red[0][cg];
        #pragma unroll
        for (int r = 1; r < 16; ++r) {
            s.x += red[r][cg].x; s.y += red[r][cg].y;
            s.z += red[r][cg].z; s.w += red[r][cg].w;
        }
        reinterpret_cast<float4*>(spart + ((size_t)cb * BB + b) * DD)[cg] = s;
    }
}

// ---------------- small kernel: per-(b,i) o, normalize, w~ (or squash->out) ----
// MODE 0: src = spart (32 partials, summed here), o=(1/32) s@W_i, l2norm, w~
// MODE 1: src = t[b][i][64], o = t @ W_i, l2norm, w~
// MODE 2: src = t[b][i][64], o = t @ W_i, squash -> out
template <int MODE>
__global__ __launch_bounds__(512) void ksmall(const float* __restrict__ src,
                                              const float* __restrict__ W,
                                              float* __restrict__ w_out,
                                              float* __restrict__ out) {
    int b = blockIdx.x;
    int tid = threadIdx.x;                  // 512 = 32 capsules x 16 dims
    int i = tid >> 4;
    int j = tid & 15;
    __shared__ float srow[DD];
    if (MODE == 0) {
        if (tid < DD) {
            float a = 0.f;
            for (int cb = 0; cb < 32; ++cb)
                a += src[((size_t)cb * BB + b) * DD + tid];
            srow[tid] = a;
        }
        __syncthreads();
    }
    const float* trow = (MODE == 0) ? srow : (src + ((size_t)b * II + i) * DD);
    float o = 0.f;
    #pragma unroll 8
    for (int d = 0; d < DD; ++d)
        o += trow[d] * W[d * (II * JJ) + i * JJ + j];
    if (MODE == 0) o *= (1.0f / 32.0f);

    float ss = o * o;
    #pragma unroll
    for (int off = 8; off >= 1; off >>= 1)
        ss += __shfl_xor(ss, off, 16);

    if (MODE == 2) {
        float s2 = ss + 1e-7f;                       // K.epsilon
        float scale = sqrtf(s2) / (0.5f + s2);       // squash
        out[((size_t)b * II + i) * JJ + j] = scale * o;
        return;
    }

    float norm = sqrtf(fmaxf(ss, 1e-12f));           // tf l2_normalize
    float ov = o / norm;
    __shared__ float osh[II][JJ];
    osh[i][j] = ov;
    __syncthreads();
    #pragma unroll
    for (int k = 0; k < 4; ++k) {
        int d = j + 16 * k;
        float acc = 0.f;
        #pragma unroll
        for (int jj = 0; jj < 16; ++jj)
            acc += W[d * (II * JJ) + i * JJ + jj] * osh[i][jj];
        w_out[((size_t)b * II + i) * DD + d] = acc;
    }
}

// ---------------- partial reduce: t[m] = sum_ch tpart[ch][m] ----------------
__global__ __launch_bounds__(256) void kred(const float* __restrict__ in,
                                            float* __restrict__ out) {
    int m = blockIdx.x * 256 + threadIdx.x;
    float acc = 0.f;
    #pragma unroll
    for (int ch = 0; ch < NCH; ++ch)
        acc += in[(size_t)ch * (BB * II * DD) + m];
    out[m] = acc;
}

// ---------------- big kernel: one routing pass (MFMA, LDS-staged) ----------
__global__ __launch_bounds__(256) void kbig(const float* __restrict__ u,
                                            const float* __restrict__ w,
                                            float* __restrict__ tpart) {
    int b = blockIdx.y;
    int chunk = blockIdx.x;                 // 0..NCH-1
    int tid = threadIdx.x;
    int wv = tid >> 6;                      // wave 0..3
    int l  = tid & 63;
    int h  = l >> 5;
    int ln = l & 31;
    int lane16 = l & 15;
    int lrow   = l >> 4;                    // 0..3

    // granule-swizzled tiles: source granule g of row r lives at g^(r&14)
    __shared__ __align__(16) float uslice[CHROWS * DD];  // 32 KB
    __shared__ __align__(16) float wlds[II * DD];        // 8 KB
    __shared__ float clds[CHROWS][II + 1];               // 16.9 KB
    __shared__ float tlds[II][DD + 1];                   // 8.3 KB

    // ---- async staging: pre-swizzled global source, linear LDS dest ----
    const float* ub = u + (size_t)b * NN * DD;
    const float* wb = w + (size_t)b * II * DD;
    #pragma unroll
    for (int k = 0; k < 8; ++k) {                 // u-slice: 8 x 1KB per wave
        int inst = wv * 8 + k;
        int row  = inst * 4 + lrow;               // 0..127
        int gran = lane16 ^ (row & 14);
        gload_lds16(&uslice[inst * 256],
                    ub + ((size_t)(chunk * CHROWS + row)) * DD + gran * 4);
    }
    #pragma unroll
    for (int k = 0; k < 2; ++k) {                 // w~: 2 x 1KB per wave
        int inst = wv * 2 + k;
        int row  = inst * 4 + lrow;               // 0..31
        int gran = lane16 ^ (row & 14);
        gload_lds16(&wlds[inst * 256], wb + (size_t)row * DD + gran * 4);
    }

    float* tldsf = &tlds[0][0];
    for (int k = tid; k < II * (DD + 1); k += 256) tldsf[k] = 0.f;

    asm volatile("s_waitcnt vmcnt(0)" ::: "memory");
    __syncthreads();

    // ---- logits: C[i][n] = sum_d w~[i][d]*u[n][d]; one 32x32 tile/wave ----
    f32x16 S;
    #pragma unroll
    for (int r = 0; r < 16; ++r) S[r] = 0.f;

    int urloc = wv * 32 + ln;                     // local u row (= n col)
    #pragma unroll
    for (int kt = 0; kt < 4; ++kt) {
        int g0 = kt * 4 + h * 2;                  // even source granule
        const float* pa = &wlds[ln * DD + (g0 ^ (ln & 14)) * 4];
        const float* pb = &uslice[urloc * DD + (g0 ^ (ln & 14)) * 4];
        float4 a0 = ((const float4*)pa)[0];
        float4 a1 = ((const float4*)pa)[1];
        float4 b0 = ((const float4*)pb)[0];
        float4 b1 = ((const float4*)pb)[1];
        bf16x8 A, Bv;
        A[0]=f2bf(a0.x); A[1]=f2bf(a0.y); A[2]=f2bf(a0.z); A[3]=f2bf(a0.w);
        A[4]=f2bf(a1.x); A[5]=f2bf(a1.y); A[6]=f2bf(a1.z); A[7]=f2bf(a1.w);
        Bv[0]=f2bf(b0.x); Bv[1]=f2bf(b0.y); Bv[2]=f2bf(b0.z); Bv[3]=f2bf(b0.w);
        Bv[4]=f2bf(b1.x); Bv[5]=f2bf(b1.y); Bv[6]=f2bf(b1.z); Bv[7]=f2bf(b1.w);
        S = __builtin_amdgcn_mfma_f32_32x32x16_bf16(A, Bv, S, 0, 0, 0);
    }

    // ---- softmax over i (lane-local 16 + partner half via xor 32) ----
    float m = S[0];
    #pragma unroll
    for (int r = 1; r < 16; ++r) m = fmaxf(m, S[r]);
    m = fmaxf(m, __shfl_xor(m, 32));
    float sum = 0.f;
    float e[16];
    #pragma unroll
    for (int r = 0; r < 16; ++r) { e[r] = __expf(S[r] - m); sum += e[r]; }
    sum += __shfl_xor(sum, 32);
    float inv = 1.f / sum;
    #pragma unroll
    for (int r = 0; r < 16; ++r) {
        int irow = (r & 3) + 8 * (r >> 2) + 4 * h;
        clds[wv * 32 + ln][irow] = e[r] * inv;    // c[n][i]
    }
    __syncthreads();

    // ---- t-GEMM: t[i][d] += sum_n c[n][i]*u[n][d]; hi/lo bf16 (3 terms) ----
    f32x16 G0, G1;
    #pragma unroll
    for (int r = 0; r < 16; ++r) { G0[r] = 0.f; G1[r] = 0.f; }

    bf16x8 Ah[2], Al[2];
    #pragma unroll
    for (int t2 = 0; t2 < 2; ++t2) {
        int nb = wv * 32 + t2 * 16 + h * 8;
        #pragma unroll
        for (int jj = 0; jj < 8; ++jj) {
            float cv = clds[nb + jj][ln];         // lanes consecutive: no conflict
            short hi = f2bf(cv);
            Ah[t2][jj] = hi;
            Al[t2][jj] = f2bf(cv - bf2f(hi));
        }
    }

    #pragma unroll
    for (int t2 = 0; t2 < 2; ++t2) {
        int nb = wv * 32 + t2 * 16 + h * 8;       // local k (row) base
        #pragma unroll
        for (int Nt = 0; Nt < 2; ++Nt) {
            bf16x8 Bh, Bl;
            #pragma unroll
            for (int jj = 0; jj < 8; ++jj) {
                int row = nb + jj;
                int gq = (Nt * 8 + (ln >> 2)) ^ (row & 14);
                float uv = uslice[row * DD + gq * 4 + (ln & 3)];  // 32 distinct banks
                short hi = f2bf(uv);
                Bh[jj] = hi;
                Bl[jj] = f2bf(uv - bf2f(hi));
            }
            if (Nt == 0) {
                G0 = __builtin_amdgcn_mfma_f32_32x32x16_bf16(Ah[t2], Bh, G0, 0, 0, 0);
                G0 = __builtin_amdgcn_mfma_f32_32x32x16_bf16(Al[t2], Bh, G0, 0, 0, 0);
                G0 = __builtin_amdgcn_mfma_f32_32x32x16_bf16(Ah[t2], Bl, G0, 0, 0, 0);
            } else {
                G1 = __builtin_amdgcn_mfma_f32_32x32x16_bf16(Ah[t2], Bh, G1, 0, 0, 0);
                G1 = __builtin_amdgcn_mfma_f32_32x32x16_bf16(Al[t2], Bh, G1, 0, 0, 0);
                G1 = __builtin_amdgcn_mfma_f32_32x32x16_bf16(Ah[t2], Bl, G1, 0, 0, 0);
            }
        }
    }

    // ---- block-local reduce (LDS atomics), then coalesced partial store ----
    #pragma unroll
    for (int r = 0; r < 16; ++r) {
        int irow = (r & 3) + 8 * (r >> 2) + 4 * h;
        atomicAdd(&tlds[irow][ln],      G0[r]);
        atomicAdd(&tlds[irow][32 + ln], G1[r]);
    }
    __syncthreads();
    float* dst = tpart + ((size_t)chunk * BB + b) * (II * DD);
    for (int k = tid; k < II * DD; k += 256)
        dst[k] = tlds[k >> 6][k & 63];
}

extern "C" void kernel_launch(void* const* d_in, const int* in_sizes, int n_in,
                              void* d_out, int out_size, void* d_ws, size_t ws_size,
                              hipStream_t stream) {
    const float* u = (const float*)d_in[0];     // (64, 2048, 64)
    const float* W = (const float*)d_in[1];     // (1, 64, 512)
    float* out = (float*)d_out;                 // (64, 32, 16)
    float* ws = (float*)d_ws;

    float* t1    = ws;                          // 131072 floats
    float* wtil  = ws + 131072;                 // 131072
    float* spart = ws + 2 * 131072;             // 131072
    float* tpart = ws + 3 * 131072;             // NCH*131072 (8 MB)
    // total 19*131072*4B = 9.96 MB (r7 proved ws >= 10.02 MB: part path ran)

    dim3 gbig(NCH, BB);
    ksum<<<dim3(32, BB), 256, 0, stream>>>(u, spart);
    ksmall<0><<<BB, 512, 0, stream>>>(spart, W, wtil, nullptr);  // iter0
    kbig<<<gbig, 256, 0, stream>>>(u, wtil, tpart);
    kred<<<BB * II * DD / 256, 256, 0, stream>>>(tpart, t1);
    ksmall<1><<<BB, 512, 0, stream>>>(t1, W, wtil, nullptr);
    kbig<<<gbig, 256, 0, stream>>>(u, wtil, tpart);
    kred<<<BB * II * DD / 256, 256, 0, stream>>>(tpart, t1);
    ksmall<2><<<BB, 512, 0, stream>>>(t1, W, nullptr, out);      // squash
}

// Round 9
// 144.908 us; speedup vs baseline: 1.0412x; 1.0412x over previous
//
#include <hip/hip_runtime.h>
#include <hip/hip_bf16.h>

// Capsule dynamic routing, factored (no u_hat), MFMA, all-clean memory access.
// B=64, N=2048, D=64, I=32, J=16.
// Round 9: every global access linear+coalesced float4; LDS via register
// staging into bf16 planes (hi/lo) with XOR swizzle d^((row&7)<<3);
// phase-1 b128 LDS frags; phase-2 u16 row reads; 52.9 KB LDS -> 3 blocks/CU.
// Diagnostic intent: if kbig stays ~55us with this provably-clean kernel,
// access-pattern theories are falsified -> persistent kernel next.

#define BB 64
#define NN 2048
#define DD 64
#define II 32
#define CHROWS 128            // rows per kbig block (4 waves x 32 rows)
#define NCH (NN / CHROWS)     // 16 chunks per batch

typedef __attribute__((ext_vector_type(8)))  short bf16x8;
typedef __attribute__((ext_vector_type(16))) float f32x16;

__device__ __forceinline__ short f2bf(float f) {
    __hip_bfloat16 h = __float2bfloat16(f);
    return *reinterpret_cast<short*>(&h);
}
__device__ __forceinline__ float bf2f(short s) {
    __hip_bfloat16 h = *reinterpret_cast<__hip_bfloat16*>(&s);
    return __bfloat162float(h);
}
__device__ __forceinline__ int sw(int row, int d) { return d ^ ((row & 7) << 3); }

// ---------------- kernel 1: spart[cb][b][d] = sum of 64 rows ----------------
__global__ __launch_bounds__(256) void ksum(const float* __restrict__ u,
                                            float* __restrict__ spart) {
    int b = blockIdx.y, cb = blockIdx.x;        // cb: 0..31, 64 rows each
    int tid = threadIdx.x, cg = tid & 15, rr = tid >> 4;
    const float4* up = reinterpret_cast<const float4*>(
        u + ((size_t)b * NN + (size_t)cb * 64 + rr) * DD) + cg;
    float4 a = {0.f, 0.f, 0.f, 0.f};
    #pragma unroll
    for (int k = 0; k < 4; ++k) {               // rows rr + 16k
        float4 v = up[(size_t)k * 16 * (DD / 4)];
        a.x += v.x; a.y += v.y; a.z += v.z; a.w += v.w;
    }
    __shared__ float4 red[16][16];
    red[rr][cg] = a;
    __syncthreads();
    if (rr == 0) {
        float4 s = red[0][cg];
        #pragma unroll
        for (int r = 1; r < 16; ++r) {
            s.x += red[r][cg].x; s.y += red[r][cg].y;
            s.z += red[r][cg].z; s.w += red[r][cg].w;
        }
        reinterpret_cast<float4*>(spart + ((size_t)cb * BB + b) * DD)[cg] = s;
    }
}

// ---------------- small kernel: per-(b,i) o, normalize, w~ (or squash->out) ----
template <int MODE>
__global__ __launch_bounds__(512) void ksmall(const float* __restrict__ src,
                                              const float* __restrict__ W,
                                              float* __restrict__ w_out,
                                              float* __restrict__ out) {
    int b = blockIdx.x;
    int tid = threadIdx.x;                  // 512 = 32 capsules x 16 dims
    int i = tid >> 4;
    int j = tid & 15;
    __shared__ float srow[DD];
    if (MODE == 0) {
        if (tid < DD) {
            float a = 0.f;
            for (int cb = 0; cb < 32; ++cb)
                a += src[((size_t)cb * BB + b) * DD + tid];
            srow[tid] = a;
        }
        __syncthreads();
    }
    const float* trow = (MODE == 0) ? srow : (src + ((size_t)b * II + i) * DD);
    float o = 0.f;
    #pragma unroll 8
    for (int d = 0; d < DD; ++d)
        o += trow[d] * W[d * (II * 16) + i * 16 + j];
    if (MODE == 0) o *= (1.0f / 32.0f);

    float ss = o * o;
    #pragma unroll
    for (int off = 8; off >= 1; off >>= 1)
        ss += __shfl_xor(ss, off, 16);

    if (MODE == 2) {
        float s2 = ss + 1e-7f;                       // K.epsilon
        float scale = sqrtf(s2) / (0.5f + s2);       // squash
        out[((size_t)b * II + i) * 16 + j] = scale * o;
        return;
    }

    float norm = sqrtf(fmaxf(ss, 1e-12f));           // tf l2_normalize
    float ov = o / norm;
    __shared__ float osh[II][16];
    osh[i][j] = ov;
    __syncthreads();
    #pragma unroll
    for (int k = 0; k < 4; ++k) {
        int d = j + 16 * k;
        float acc = 0.f;
        #pragma unroll
        for (int jj = 0; jj < 16; ++jj)
            acc += W[d * (II * 16) + i * 16 + jj] * osh[i][jj];
        w_out[((size_t)b * II + i) * DD + d] = acc;
    }
}

// ---------------- partial reduce: t[m] = sum_ch tpart[ch][m] ----------------
__global__ __launch_bounds__(256) void kred(const float* __restrict__ in,
                                            float* __restrict__ out) {
    int m = blockIdx.x * 256 + threadIdx.x;
    float acc = 0.f;
    #pragma unroll
    for (int ch = 0; ch < NCH; ++ch)
        acc += in[(size_t)ch * (BB * II * DD) + m];
    out[m] = acc;
}

// ---------------- big kernel: one routing pass (MFMA, clean access) --------
__global__ __launch_bounds__(256) void kbig(const float* __restrict__ u,
                                            const float* __restrict__ w,
                                            float* __restrict__ tpart) {
    int b = blockIdx.y;
    int chunk = blockIdx.x;                 // 0..NCH-1
    int tid = threadIdx.x;
    int wv = tid >> 6, l = tid & 63, h = l >> 5, ln = l & 31;

    __shared__ unsigned short uhi[CHROWS * DD];   // 16 KB  bf16(u)
    __shared__ unsigned short ulo[CHROWS * DD];   // 16 KB  bf16(u - hi)
    __shared__ unsigned short whi[II * DD];       // 4 KB   bf16(w~)
    __shared__ float cbuf[CHROWS][II + 1];        // 16.9 KB; reused as tlds

    // ---- staging: linear coalesced float4 -> registers -> swizzled planes ----
    const float4* ub4 = reinterpret_cast<const float4*>(
        u + ((size_t)b * NN + (size_t)chunk * CHROWS) * DD);
    #pragma unroll
    for (int k = 0; k < 8; ++k) {
        int gidx = k * 256 + tid;           // float4 index, 2048 total
        int row  = gidx >> 4;
        int d0   = (gidx & 15) * 4;
        float4 v = ub4[gidx];
        short h0=f2bf(v.x), h1=f2bf(v.y), h2=f2bf(v.z), h3=f2bf(v.w);
        short s0=f2bf(v.x-bf2f(h0)), s1=f2bf(v.y-bf2f(h1)),
              s2=f2bf(v.z-bf2f(h2)), s3=f2bf(v.w-bf2f(h3));
        int idx = row * DD + sw(row, d0);   // multiple of 4 -> 8B aligned
        uint2 ph = { (unsigned)(unsigned short)h0 | ((unsigned)(unsigned short)h1 << 16),
                     (unsigned)(unsigned short)h2 | ((unsigned)(unsigned short)h3 << 16) };
        uint2 pl = { (unsigned)(unsigned short)s0 | ((unsigned)(unsigned short)s1 << 16),
                     (unsigned)(unsigned short)s2 | ((unsigned)(unsigned short)s3 << 16) };
        *reinterpret_cast<uint2*>(&uhi[idx]) = ph;
        *reinterpret_cast<uint2*>(&ulo[idx]) = pl;
    }
    const float4* wb4 = reinterpret_cast<const float4*>(w + (size_t)b * II * DD);
    #pragma unroll
    for (int k = 0; k < 2; ++k) {
        int gidx = k * 256 + tid;           // 512 float4 total
        int row  = gidx >> 4;
        int d0   = (gidx & 15) * 4;
        float4 v = wb4[gidx];
        short h0=f2bf(v.x), h1=f2bf(v.y), h2=f2bf(v.z), h3=f2bf(v.w);
        int idx = row * DD + sw(row, d0);
        uint2 ph = { (unsigned)(unsigned short)h0 | ((unsigned)(unsigned short)h1 << 16),
                     (unsigned)(unsigned short)h2 | ((unsigned)(unsigned short)h3 << 16) };
        *reinterpret_cast<uint2*>(&whi[idx]) = ph;
    }
    __syncthreads();

    // ---- phase 1: logits C[i][n] = sum_d w~[i][d]*u[n][d]; 32x32 tile/wave ----
    f32x16 S;
    #pragma unroll
    for (int r = 0; r < 16; ++r) S[r] = 0.f;
    int nloc = wv * 32 + ln;
    #pragma unroll
    for (int kt = 0; kt < 4; ++kt) {
        int d0 = kt * 16 + h * 8;           // multiple of 8 -> 16B aligned reads
        bf16x8 A  = *reinterpret_cast<const bf16x8*>(&whi[ln * DD + sw(ln, d0)]);
        bf16x8 Bv = *reinterpret_cast<const bf16x8*>(&uhi[nloc * DD + sw(nloc, d0)]);
        S = __builtin_amdgcn_mfma_f32_32x32x16_bf16(A, Bv, S, 0, 0, 0);
    }

    // ---- softmax over i (16 lane-local + partner half via xor 32) ----
    float m = S[0];
    #pragma unroll
    for (int r = 1; r < 16; ++r) m = fmaxf(m, S[r]);
    m = fmaxf(m, __shfl_xor(m, 32));
    float sum = 0.f;
    float e[16];
    #pragma unroll
    for (int r = 0; r < 16; ++r) { e[r] = __expf(S[r] - m); sum += e[r]; }
    sum += __shfl_xor(sum, 32);
    float inv = 1.f / sum;
    #pragma unroll
    for (int r = 0; r < 16; ++r) {
        int irow = (r & 3) + 8 * (r >> 2) + 4 * h;
        cbuf[nloc][irow] = e[r] * inv;      // banks (n*33+i): conflict-free
    }
    __syncthreads();

    // ---- phase 2: t[i][d] += sum_n c[n][i]*u[n][d]; 3-term hi/lo bf16 ----
    f32x16 G0, G1;
    #pragma unroll
    for (int r = 0; r < 16; ++r) { G0[r] = 0.f; G1[r] = 0.f; }

    bf16x8 Ah[2], Al[2];
    #pragma unroll
    for (int t2 = 0; t2 < 2; ++t2) {
        int nb = wv * 32 + t2 * 16 + h * 8;
        #pragma unroll
        for (int jj = 0; jj < 8; ++jj) {
            float cv = cbuf[nb + jj][ln];
            short hi = f2bf(cv);
            Ah[t2][jj] = hi;
            Al[t2][jj] = f2bf(cv - bf2f(hi));
        }
    }

    #pragma unroll
    for (int t2 = 0; t2 < 2; ++t2) {
        int nb = wv * 32 + t2 * 16 + h * 8;
        #pragma unroll
        for (int Nt = 0; Nt < 2; ++Nt) {
            bf16x8 Bh, Bl;
            #pragma unroll
            for (int jj = 0; jj < 8; ++jj) {
                int row = nb + jj;
                int idx = row * DD + sw(row, Nt * 32 + ln);
                Bh[jj] = (short)uhi[idx];   // row-fixed u16 reads
                Bl[jj] = (short)ulo[idx];
            }
            if (Nt == 0) {
                G0 = __builtin_amdgcn_mfma_f32_32x32x16_bf16(Ah[t2], Bh, G0, 0, 0, 0);
                G0 = __builtin_amdgcn_mfma_f32_32x32x16_bf16(Al[t2], Bh, G0, 0, 0, 0);
                G0 = __builtin_amdgcn_mfma_f32_32x32x16_bf16(Ah[t2], Bl, G0, 0, 0, 0);
            } else {
                G1 = __builtin_amdgcn_mfma_f32_32x32x16_bf16(Ah[t2], Bh, G1, 0, 0, 0);
                G1 = __builtin_amdgcn_mfma_f32_32x32x16_bf16(Al[t2], Bh, G1, 0, 0, 0);
                G1 = __builtin_amdgcn_mfma_f32_32x32x16_bf16(Ah[t2], Bl, G1, 0, 0, 0);
            }
        }
    }
    __syncthreads();                         // all reads of cbuf/uhi done

    // ---- block reduce: reuse cbuf as tlds[32][65], then coalesced store ----
    float (*tlds)[65] = reinterpret_cast<float(*)[65]>(&cbuf[0][0]);
    for (int k = tid; k < II * 65; k += 256) (&tlds[0][0])[k] = 0.f;
    __syncthreads();
    #pragma unroll
    for (int r = 0; r < 16; ++r) {
        int irow = (r & 3) + 8 * (r >> 2) + 4 * h;
        atomicAdd(&tlds[irow][ln],      G0[r]);
        atomicAdd(&tlds[irow][32 + ln], G1[r]);
    }
    __syncthreads();
    float* dst = tpart + ((size_t)chunk * BB + b) * (II * DD);
    for (int k = tid; k < II * DD; k += 256)
        dst[k] = tlds[k >> 6][k & 63];
}

extern "C" void kernel_launch(void* const* d_in, const int* in_sizes, int n_in,
                              void* d_out, int out_size, void* d_ws, size_t ws_size,
                              hipStream_t stream) {
    const float* u = (const float*)d_in[0];     // (64, 2048, 64)
    const float* W = (const float*)d_in[1];     // (1, 64, 512)
    float* out = (float*)d_out;                 // (64, 32, 16)
    float* ws = (float*)d_ws;

    float* t1    = ws;                          // 131072 floats
    float* wtil  = ws + 131072;                 // 131072
    float* spart = ws + 2 * 131072;             // 131072
    float* tpart = ws + 3 * 131072;             // NCH*131072 (8 MB)
    // total 9.96 MB; r8 ran this footprint successfully.

    dim3 gbig(NCH, BB);
    ksum<<<dim3(32, BB), 256, 0, stream>>>(u, spart);
    ksmall<0><<<BB, 512, 0, stream>>>(spart, W, wtil, nullptr);  // iter0
    kbig<<<gbig, 256, 0, stream>>>(u, wtil, tpart);
    kred<<<BB * II * DD / 256, 256, 0, stream>>>(tpart, t1);
    ksmall<1><<<BB, 512, 0, stream>>>(t1, W, wtil, nullptr);
    kbig<<<gbig, 256, 0, stream>>>(u, wtil, tpart);
    kred<<<BB * II * DD / 256, 256, 0, stream>>>(tpart, t1);
    ksmall<2><<<BB, 512, 0, stream>>>(t1, W, nullptr, out);      // squash
}

// Round 10
// 100.849 us; speedup vs baseline: 1.4961x; 1.4369x over previous
//
#include <hip/hip_runtime.h>
#include <hip/hip_bf16.h>

// Capsule dynamic routing — ENTIRE op in ONE kernel dispatch.
// Diagnostic r10: r3..r9 all show a structure-independent ~55us floor per
// kbig dispatch with every pipe <7% busy; access-pattern fixes (clean
// coalescing, no atomics, gload_lds, swizzles) all null. Remaining theory:
// per-dispatch / inter-dispatch overhead. Test: batches are independent ->
// one block per b does everything (no grid sync needed). 64 blocks x 512
// threads, ~119 KB LDS, 1 block/CU. Math is verbatim r6/r9 (absmax 0.0039).
//
// Per block (batch b):
//   A: s[d] = sum_n u[n,d]            (wave-parallel, shfl reduce)
//   B: o0 = (1/32) s @ W_i, l2norm -> w~ in LDS        (ksmall<0> inline)
//   loop it=0,1:
//     per wave, 8 tiles of 32 rows:
//       row-frags u (global, per-lane row) -> bf16 hi/lo regs + swizzled LDS
//       logits S = mfma(w~, u^T)  (C cols = n = lane -> softmax lane-local)
//       c -> per-wave slab;  t-GEMM: G += mfma(c^T, u) 3-term hi/lo
//     flush G -> tlds (LDS atomics), barrier
//     it=0: o,l2norm,w~ update, re-zero tlds   (ksmall<1> inline)
//     it=1: squash -> out                      (ksmall<2> inline)

#define BB 64
#define NN 2048
#define DD 64
#define II 32

typedef __attribute__((ext_vector_type(8)))  short bf16x8;
typedef __attribute__((ext_vector_type(16))) float f32x16;

__device__ __forceinline__ short f2bf(float f) {
    __hip_bfloat16 h = __float2bfloat16(f);
    return *reinterpret_cast<short*>(&h);
}
__device__ __forceinline__ float bf2f(short s) {
    __hip_bfloat16 h = *reinterpret_cast<__hip_bfloat16*>(&s);
    return __bfloat162float(h);
}

__global__ __launch_bounds__(512) void kall(const float* __restrict__ u,
                                            const float* __restrict__ W,
                                            float* __restrict__ out) {
    int b = blockIdx.x;
    int tid = threadIdx.x;
    int wv = tid >> 6;                  // wave 0..7, owns rows [wv*256, +256)
    int l = tid & 63, h = l >> 5, ln = l & 31;
    int ii = tid >> 4, jj0 = tid & 15;  // ksmall mapping: capsule i, dim j

    __shared__ unsigned short ush[8][2048];   // 32 KB per-wave u-tile bf16 hi
    __shared__ unsigned short usl[8][2048];   // 32 KB lo plane
    __shared__ float cslab[8][II * 33];       // 33.8 KB per-wave c[n][i]
    __shared__ float tlds[II][65];            // 8.3 KB t reduce
    __shared__ float wlds[II][68];            // 8.7 KB w~
    __shared__ float slds[8][DD];             // 2 KB s partials
    __shared__ float ssum[DD];                // 256 B
    __shared__ float osh[II][16];             // 2 KB

    const float* ubase = u + (size_t)b * NN * DD;

    // ---- phase A: s[d] = sum_n u[n][d] ----
    {
        const float4* up = reinterpret_cast<const float4*>(ubase + (size_t)wv * 256 * DD);
        int r0 = l >> 4, c4 = l & 15;         // 4 rows x 16 float4-cols per step
        float4 a0 = {0.f, 0.f, 0.f, 0.f};
        #pragma unroll 8
        for (int s = 0; s < 64; ++s) {
            float4 v = up[(s * 4 + r0) * 16 + c4];
            a0.x += v.x; a0.y += v.y; a0.z += v.z; a0.w += v.w;
        }
        #pragma unroll
        for (int off = 16; off <= 32; off <<= 1) {
            a0.x += __shfl_xor(a0.x, off);
            a0.y += __shfl_xor(a0.y, off);
            a0.z += __shfl_xor(a0.z, off);
            a0.w += __shfl_xor(a0.w, off);
        }
        if (l < 16) *reinterpret_cast<float4*>(&slds[wv][l * 4]) = a0;
    }
    for (int k = tid; k < II * 65; k += 512) (&tlds[0][0])[k] = 0.f;
    __syncthreads();

    // ---- phase B: o0 = (1/32) s @ W, l2norm, w~ ----
    if (tid < DD) {
        float a = 0.f;
        #pragma unroll
        for (int wq = 0; wq < 8; ++wq) a += slds[wq][tid];
        ssum[tid] = a;
    }
    __syncthreads();
    {
        float o = 0.f;
        #pragma unroll 8
        for (int d = 0; d < DD; ++d) o += ssum[d] * W[d * 512 + ii * 16 + jj0];
        o *= (1.0f / 32.0f);
        float ss = o * o;
        #pragma unroll
        for (int off = 8; off >= 1; off >>= 1) ss += __shfl_xor(ss, off, 16);
        osh[ii][jj0] = o / sqrtf(fmaxf(ss, 1e-12f));
    }
    __syncthreads();
    #pragma unroll
    for (int k = 0; k < 4; ++k) {
        int d = jj0 + 16 * k;
        float acc = 0.f;
        #pragma unroll
        for (int j2 = 0; j2 < 16; ++j2)
            acc += W[d * 512 + ii * 16 + j2] * osh[ii][j2];
        wlds[ii][d] = acc;
    }
    __syncthreads();

    // ---- routing iterations ----
    for (int it = 0; it < 2; ++it) {
        // w~ A-frags: lane ln = row i, k-run = d
        bf16x8 Aw[4];
        #pragma unroll
        for (int kt = 0; kt < 4; ++kt) {
            const float* p = &wlds[ln][kt * 16 + h * 8];
            #pragma unroll
            for (int e2 = 0; e2 < 8; ++e2) Aw[kt][e2] = f2bf(p[e2]);
        }
        f32x16 G0, G1;
        #pragma unroll
        for (int r = 0; r < 16; ++r) { G0[r] = 0.f; G1[r] = 0.f; }

        for (int tt = 0; tt < 8; ++tt) {
            int n0 = wv * 256 + tt * 32;
            // row-frag load (global) + hi/lo cvt + swizzled slab store
            bf16x8 Bh[4], Bl[4];
            #pragma unroll
            for (int kt = 0; kt < 4; ++kt) {
                const float4* p = reinterpret_cast<const float4*>(
                    ubase + (size_t)(n0 + ln) * DD + kt * 16 + h * 8);
                float4 v0 = p[0], v1 = p[1];
                float vf[8] = {v0.x, v0.y, v0.z, v0.w, v1.x, v1.y, v1.z, v1.w};
                #pragma unroll
                for (int e2 = 0; e2 < 8; ++e2) {
                    short hi = f2bf(vf[e2]);
                    Bh[kt][e2] = hi;
                    Bl[kt][e2] = f2bf(vf[e2] - bf2f(hi));
                }
                int d0 = kt * 16 + h * 8;
                int idx = ln * 64 + (d0 ^ ((ln & 7) << 3));
                *reinterpret_cast<bf16x8*>(&ush[wv][idx]) = Bh[kt];
                *reinterpret_cast<bf16x8*>(&usl[wv][idx]) = Bl[kt];
            }
            // logits: C[i][n], col = ln
            f32x16 S;
            #pragma unroll
            for (int r = 0; r < 16; ++r) S[r] = 0.f;
            #pragma unroll
            for (int kt = 0; kt < 4; ++kt)
                S = __builtin_amdgcn_mfma_f32_32x32x16_bf16(Aw[kt], Bh[kt], S, 0, 0, 0);
            // softmax over i: 16 lane-local + partner half (xor 32)
            float m = S[0];
            #pragma unroll
            for (int r = 1; r < 16; ++r) m = fmaxf(m, S[r]);
            m = fmaxf(m, __shfl_xor(m, 32));
            float sum = 0.f, e[16];
            #pragma unroll
            for (int r = 0; r < 16; ++r) { e[r] = __expf(S[r] - m); sum += e[r]; }
            sum += __shfl_xor(sum, 32);
            float inv = 1.f / sum;
            #pragma unroll
            for (int r = 0; r < 16; ++r) {
                int irow = (r & 3) + 8 * (r >> 2) + 4 * h;
                cslab[wv][ln * 33 + irow] = e[r] * inv;   // c[n=ln][i]
            }
            // t-GEMM: A = c^T (lane=row i), B = u cols (lane=col d)
            #pragma unroll
            for (int t2 = 0; t2 < 2; ++t2) {
                bf16x8 Ah, Al;
                #pragma unroll
                for (int q = 0; q < 8; ++q) {
                    float cv = cslab[wv][(t2 * 16 + h * 8 + q) * 33 + ln];
                    short hi = f2bf(cv);
                    Ah[q] = hi;
                    Al[q] = f2bf(cv - bf2f(hi));
                }
                #pragma unroll
                for (int Nt = 0; Nt < 2; ++Nt) {
                    bf16x8 B2h, B2l;
                    #pragma unroll
                    for (int q = 0; q < 8; ++q) {
                        int row = t2 * 16 + h * 8 + q;
                        int idx = row * 64 + ((Nt * 32 + ln) ^ ((row & 7) << 3));
                        B2h[q] = (short)ush[wv][idx];
                        B2l[q] = (short)usl[wv][idx];
                    }
                    if (Nt == 0) {
                        G0 = __builtin_amdgcn_mfma_f32_32x32x16_bf16(Ah, B2h, G0, 0, 0, 0);
                        G0 = __builtin_amdgcn_mfma_f32_32x32x16_bf16(Al, B2h, G0, 0, 0, 0);
                        G0 = __builtin_amdgcn_mfma_f32_32x32x16_bf16(Ah, B2l, G0, 0, 0, 0);
                    } else {
                        G1 = __builtin_amdgcn_mfma_f32_32x32x16_bf16(Ah, B2h, G1, 0, 0, 0);
                        G1 = __builtin_amdgcn_mfma_f32_32x32x16_bf16(Al, B2h, G1, 0, 0, 0);
                        G1 = __builtin_amdgcn_mfma_f32_32x32x16_bf16(Ah, B2l, G1, 0, 0, 0);
                    }
                }
            }
        }
        // flush t (cross-wave LDS reduce)
        #pragma unroll
        for (int r = 0; r < 16; ++r) {
            int irow = (r & 3) + 8 * (r >> 2) + 4 * h;
            atomicAdd(&tlds[irow][ln],      G0[r]);
            atomicAdd(&tlds[irow][32 + ln], G1[r]);
        }
        __syncthreads();

        // epilogue: o = t @ W_i  (+ l2norm->w~  or  squash->out)
        float o = 0.f;
        #pragma unroll 8
        for (int d = 0; d < DD; ++d) o += tlds[ii][d] * W[d * 512 + ii * 16 + jj0];
        float ss = o * o;
        #pragma unroll
        for (int off = 8; off >= 1; off >>= 1) ss += __shfl_xor(ss, off, 16);

        if (it == 0) {
            float ov = o / sqrtf(fmaxf(ss, 1e-12f));     // tf l2_normalize
            __syncthreads();                              // all tlds reads done
            osh[ii][jj0] = ov;
            __syncthreads();
            #pragma unroll
            for (int k = 0; k < 4; ++k) {
                int d = jj0 + 16 * k;
                float acc = 0.f;
                #pragma unroll
                for (int j2 = 0; j2 < 16; ++j2)
                    acc += W[d * 512 + ii * 16 + j2] * osh[ii][j2];
                wlds[ii][d] = acc;                        // safe: all waves past Aw
            }
            for (int k = tid; k < II * 65; k += 512) (&tlds[0][0])[k] = 0.f;
            __syncthreads();
        } else {
            float s2 = ss + 1e-7f;                        // K.epsilon
            float scale = sqrtf(s2) / (0.5f + s2);        // squash
            out[(size_t)b * 512 + tid] = scale * o;
        }
    }
}

extern "C" void kernel_launch(void* const* d_in, const int* in_sizes, int n_in,
                              void* d_out, int out_size, void* d_ws, size_t ws_size,
                              hipStream_t stream) {
    const float* u = (const float*)d_in[0];     // (64, 2048, 64)
    const float* W = (const float*)d_in[1];     // (1, 64, 512)
    float* out = (float*)d_out;                 // (64, 32, 16)
    (void)d_ws; (void)ws_size;                  // no workspace needed

    kall<<<BB, 512, 0, stream>>>(u, W, out);    // ONE dispatch total
}